// Round 1
// 229.270 us; speedup vs baseline: 1.0003x; 1.0003x over previous
//
#include <hip/hip_runtime.h>

#define ROW_LEN 2048
#define BLOCK   256
#define ROWS_PER_BLOCK 4   // one 64-lane wave per row; 4 independent waves per block
#define EPS     1e-5f

__global__ __launch_bounds__(BLOCK) void RMSNorm_56607668961691_kernel(
    const float* __restrict__ x,
    const float* __restrict__ g,
    float* __restrict__ out)
{
    const int wave = threadIdx.x >> 6;
    const int lane = threadIdx.x & 63;
    const size_t row = (size_t)blockIdx.x * ROWS_PER_BLOCK + wave;

    const float4* __restrict__ xr   = reinterpret_cast<const float4*>(x + row * ROW_LEN) + lane;
    float4* __restrict__       outr = reinterpret_cast<float4*>(out + row * ROW_LEN) + lane;
    const float4* __restrict__ gv   = reinterpret_cast<const float4*>(g) + lane;

    // 2048 floats = 512 float4 = 64 lanes x 8 float4 each, coalesced (1 KiB/wave/instr).
    // All 8 loads issued back-to-back: 128 B in flight per lane.
    float4 v[8];
    #pragma unroll
    for (int j = 0; j < 8; ++j) v[j] = xr[j * 64];

    // 4 independent accumulator chains for VALU ILP.
    float s0 = 0.f, s1 = 0.f, s2 = 0.f, s3 = 0.f;
    #pragma unroll
    for (int j = 0; j < 8; ++j) {
        s0 += v[j].x * v[j].x;
        s1 += v[j].y * v[j].y;
        s2 += v[j].z * v[j].z;
        s3 += v[j].w * v[j].w;
    }
    float ss = (s0 + s1) + (s2 + s3);

    // 64-lane butterfly: every lane ends with the row total. No LDS, no barrier.
    #pragma unroll
    for (int off = 32; off > 0; off >>= 1)
        ss += __shfl_xor(ss, off, 64);

    const float scale = rsqrtf(ss * (1.0f / (float)ROW_LEN) + EPS);

    // g is 8 KiB, L1-resident after the first blocks; load just-in-time to keep
    // VGPR pressure down (x stays in registers, read exactly once from HBM).
    #pragma unroll
    for (int j = 0; j < 8; ++j) {
        const float4 gj = gv[j * 64];
        float4 o;
        o.x = v[j].x * scale * gj.x;
        o.y = v[j].y * scale * gj.y;
        o.z = v[j].z * scale * gj.z;
        o.w = v[j].w * scale * gj.w;
        outr[j * 64] = o;
    }
}

extern "C" void kernel_launch(void* const* d_in, const int* in_sizes, int n_in,
                              void* d_out, int out_size, void* d_ws, size_t ws_size,
                              hipStream_t stream) {
    const float* x = (const float*)d_in[0];
    const float* g = (const float*)d_in[1];
    float* out = (float*)d_out;

    const int rows = in_sizes[0] / ROW_LEN;          // 4*4096 = 16384
    const int grid = rows / ROWS_PER_BLOCK;          // 4096 blocks, 16/CU
    RMSNorm_56607668961691_kernel<<<grid, BLOCK, 0, stream>>>(x, g, out);
}